// Round 5
// baseline (523.203 us; speedup 1.0000x reference)
//
#include <hip/hip_runtime.h>
#include <cstdint>
#include <cstddef>

// Problem constants
#define BQ 8
#define CDIM 64
#define HQ 64
#define WQ 64
#define KDIM 512
#define N_SIG 32768   // B*H*W
#define S_NNZ 4

// d_out float offsets (outputs concatenated flat in return order)
#define DIFF_ENC_OFF 2097152
#define DIFF_DICT_OFF 2097153
#define IDS_OFF 2097154
#define NUM_STEPS_OFF 18874370
#define MEAN_D_OFF 18874371
#define MEAN_Z_OFF 18874372
#define NORM_Z_OFF 18874373
#define TOP_PCT_OFF 18874374
#define NUM_ZEROS_OFF 18874375

// ws float-offsets
// words [0..3]  : accs[2] doubles: sumAbsZ, sumSq (zeroed by k_ga block 0)
// words [4..8]  : hist[5] ints                    (zeroed by k_ga block 0)
// word  [9]     : ticket counter                  (zeroed by k_ga block 0)
// [16..24)      : pd[8] per-diagonal-block |Dn| partial sums
#define WS_PD 16
#define WS_DNT 24
#define WS_G 32792
#define WS_WG 294936   // float4 per signal (deduped gamma)
#define WS_WI 426008   // int4 per signal (idx)

typedef float v2f __attribute__((ext_vector_type(2)));

// ---- fused GEMM, self-normalizing:
//   blocks 0..63    : G = Dn^T Dn (8x8 tiles of 64); diagonal blocks also emit DnT + pd
//   blocks 64..4159 : alpha0 = X @ Dn (512 bh-tiles x 8 n-tiles)
__global__ __launch_bounds__(256) void k_ga(const float* __restrict__ X,
                                            const float* __restrict__ D,
                                            float* __restrict__ A0,
                                            float* __restrict__ G,
                                            float* __restrict__ DnT,
                                            float* __restrict__ pd,
                                            float* __restrict__ W) {
  __shared__ float Xs[64 * 65];
  __shared__ float Dns[64 * 64];
  __shared__ float partA[4][64];
  __shared__ float partB[4][64];
  __shared__ float invA[64];
  __shared__ float invB[64];
  int tid = threadIdx.x;
  int w = tid & 63, cq = tid >> 6;
  int ty = tid >> 4, tx = tid & 15;
  if (blockIdx.x == 0 && tid < 16) ((unsigned int*)W)[tid] = 0u;  // accs+hist+ticket

  if (blockIdx.x < 64) {
    // ---------------- Gram tile (ti,tj) of 64x64 ----------------
    int ti = (int)blockIdx.x >> 3, tj = (int)blockIdx.x & 7;
#pragma unroll
    for (int p = 0; p < 16; ++p) {
      int c = p * 4 + cq;
      Xs[c * 64 + w] = D[(size_t)c * KDIM + ti * 64 + w];
      Dns[c * 64 + w] = D[(size_t)c * KDIM + tj * 64 + w];
    }
    __syncthreads();
    // column norms of both tiles (4 partials per column)
    float ssA = 0.f, ssB = 0.f;
#pragma unroll
    for (int cc = 0; cc < 16; ++cc) {
      int c = cq * 16 + cc;
      float a = Xs[c * 64 + w];
      ssA = fmaf(a, a, ssA);
      float bv = Dns[c * 64 + w];
      ssB = fmaf(bv, bv, ssB);
    }
    partA[cq][w] = ssA;
    partB[cq][w] = ssB;
    __syncthreads();
    if (tid < 64) {
      invA[tid] = 1.0f / sqrtf(partA[0][tid] + partA[1][tid] + partA[2][tid] + partA[3][tid]);
      invB[tid] = 1.0f / sqrtf(partB[0][tid] + partB[1][tid] + partB[2][tid] + partB[3][tid]);
    }
    __syncthreads();
    if (ti == tj) {
      // emit normalized DnT rows ti*64..+63 and pd[ti] = sum|Dn| partial
      int kl = tid >> 2, cp = (tid & 3) * 16;
      float ia = invA[kl];
      float sabs = 0.f;
#pragma unroll
      for (int i = 0; i < 16; ++i) {
        int c = cp + i;
        float v = Xs[c * 64 + kl] * ia;
        DnT[(size_t)(ti * 64 + kl) * CDIM + c] = v;
        sabs += fabsf(v);
      }
#pragma unroll
      for (int off = 32; off >= 1; off >>= 1) sabs += __shfl_xor(sabs, off);
      __syncthreads();
      if ((tid & 63) == 0) partA[0][tid >> 6] = sabs;
      __syncthreads();
      if (tid == 0) pd[ti] = partA[0][0] + partA[0][1] + partA[0][2] + partA[0][3];
    }
    // gram main loop on raw tiles
    v2f acc[4][2] = {};
    for (int c = 0; c < 64; ++c) {
      float4 avv = *(const float4*)&Xs[c * 64 + ty * 4];
      float av[4] = {avv.x, avv.y, avv.z, avv.w};
      float4 bv = *(const float4*)&Dns[c * 64 + tx * 4];
      v2f b0 = {bv.x, bv.y}, b1 = {bv.z, bv.w};
#pragma unroll
      for (int i = 0; i < 4; ++i) {
        v2f a2 = {av[i], av[i]};
        acc[i][0] = __builtin_elementwise_fma(a2, b0, acc[i][0]);
        acc[i][1] = __builtin_elementwise_fma(a2, b1, acc[i][1]);
      }
    }
    float sn[4] = {invB[tx * 4], invB[tx * 4 + 1], invB[tx * 4 + 2], invB[tx * 4 + 3]};
#pragma unroll
    for (int i = 0; i < 4; ++i) {
      float im = invA[ty * 4 + i];
      float4 st = make_float4(acc[i][0].x * im * sn[0], acc[i][0].y * im * sn[1],
                              acc[i][1].x * im * sn[2], acc[i][1].y * im * sn[3]);
      *(float4*)&G[(size_t)(ti * 64 + ty * 4 + i) * KDIM + tj * 64 + tx * 4] = st;
    }
  } else {
    // ---------------- alpha0 tile: 64 signals x 64 atoms ----------------
    int bb = (int)blockIdx.x - 64;
    int mt = bb >> 3, nt = bb & 7;
    int b = mt >> 6, h = mt & 63;
#pragma unroll
    for (int p = 0; p < 16; ++p) {
      int c = p * 4 + cq;
      Xs[w * 65 + c] = X[(((size_t)b * CDIM + c) * HQ + h) * WQ + w];
      Dns[c * 64 + w] = D[(size_t)c * KDIM + nt * 64 + w];
    }
    __syncthreads();
    float ssB = 0.f;
#pragma unroll
    for (int cc = 0; cc < 16; ++cc) {
      int c = cq * 16 + cc;
      float bv = Dns[c * 64 + w];
      ssB = fmaf(bv, bv, ssB);
    }
    partB[cq][w] = ssB;
    __syncthreads();
    if (tid < 64)
      invB[tid] = 1.0f / sqrtf(partB[0][tid] + partB[1][tid] + partB[2][tid] + partB[3][tid]);
    __syncthreads();
    v2f acc[4][2] = {};
    for (int c = 0; c < 64; ++c) {
      float av[4];
#pragma unroll
      for (int i = 0; i < 4; ++i) av[i] = Xs[(ty * 4 + i) * 65 + c];
      float4 bv = *(const float4*)&Dns[c * 64 + tx * 4];
      v2f b0 = {bv.x, bv.y}, b1 = {bv.z, bv.w};
#pragma unroll
      for (int i = 0; i < 4; ++i) {
        v2f a2 = {av[i], av[i]};
        acc[i][0] = __builtin_elementwise_fma(a2, b0, acc[i][0]);
        acc[i][1] = __builtin_elementwise_fma(a2, b1, acc[i][1]);
      }
    }
    float sn[4] = {invB[tx * 4], invB[tx * 4 + 1], invB[tx * 4 + 2], invB[tx * 4 + 3]};
    size_t n0 = (size_t)mt * 64;
#pragma unroll
    for (int i = 0; i < 4; ++i) {
      float4 st = make_float4(acc[i][0].x * sn[0], acc[i][0].y * sn[1],
                              acc[i][1].x * sn[2], acc[i][1].y * sn[3]);
      *(float4*)&A0[(n0 + ty * 4 + i) * KDIM + nt * 64 + tx * 4] = st;
    }
  }
}

// ---- fp32 solve, no pivoting (G_II near-identity), saved reciprocals ----
template <int SZ>
__device__ __forceinline__ void solve_sz(const float (&gs)[4][4], const float (&rhs)[4],
                                         float (&gamma)[4]) {
  float M[SZ][SZ];
  float y[SZ];
  float idg[SZ];
#pragma unroll
  for (int a = 0; a < SZ; ++a) {
    y[a] = rhs[a];
#pragma unroll
    for (int b = 0; b < SZ; ++b) M[a][b] = gs[a][b] + (a == b ? 1e-7f : 0.0f);
  }
#pragma unroll
  for (int p = 0; p < SZ; ++p) {
    float ip = __builtin_amdgcn_rcpf(M[p][p]);
    idg[p] = ip;
#pragma unroll
    for (int r = p + 1; r < SZ; ++r) {
      float f = M[r][p] * ip;
#pragma unroll
      for (int c = p + 1; c < SZ; ++c) M[r][c] = fmaf(-f, M[p][c], M[r][c]);
      y[r] = fmaf(-f, y[p], y[r]);
    }
  }
#pragma unroll
  for (int r = SZ - 1; r >= 0; --r) {
    float t = y[r];
#pragma unroll
    for (int c = r + 1; c < SZ; ++c) t = fmaf(-M[r][c], gamma[c], t);
    gamma[r] = t * idg[r];
  }
}

template <int K>
__device__ __forceinline__ void omp_step(int lane, int n, const float* __restrict__ G,
                                         const float* __restrict__ A0,
                                         float (&a0)[8], float (&al)[8], float (&Grow)[3][8],
                                         float (&gs)[4][4], float (&rhs)[4], int (&idx)[4],
                                         float (&gamma)[4]) {
  // argmax |al| over 512, first-occurrence (lowest k) wins
  float mx = fabsf(al[0]);
#pragma unroll
  for (int m = 1; m < 8; ++m) mx = fmaxf(mx, fabsf(al[m]));
#pragma unroll
  for (int off = 32; off >= 1; off >>= 1) mx = fmaxf(mx, __shfl_xor(mx, off));
  int sk = 1 << 30;
#pragma unroll
  for (int m = 0; m < 8; ++m) {
    unsigned long long bm = __ballot(fabsf(al[m]) == mx);
    if (bm) {
      int kk = (int)__builtin_ctzll(bm) * 8 + m;
      sk = kk < sk ? kk : sk;
    }
  }
  idx[K] = sk;  // wave-uniform (derived from ballots)

  const float* grow_base = G + (size_t)sk * KDIM;
  if constexpr (K < 3) {
    const float4* gp = (const float4*)(grow_base + lane * 8);
    float4 r0 = gp[0], r1 = gp[1];
    Grow[K][0] = r0.x; Grow[K][1] = r0.y; Grow[K][2] = r0.z; Grow[K][3] = r0.w;
    Grow[K][4] = r1.x; Grow[K][5] = r1.y; Grow[K][6] = r1.z; Grow[K][7] = r1.w;
  }

#pragma unroll
  for (int b = 0; b < K; ++b) {
    float v = grow_base[idx[b]];
    gs[K][b] = v;
    gs[b][K] = v;
  }
  gs[K][K] = grow_base[sk];
  rhs[K] = A0[(size_t)n * KDIM + sk];

  solve_sz<K + 1>(gs, rhs, gamma);

  if constexpr (K < 3) {
#pragma unroll
    for (int m = 0; m < 8; ++m) {
      float acc = a0[m];
#pragma unroll
      for (int a = 0; a <= K; ++a) acc = fmaf(-gamma[a], Grow[a][m], acc);
      al[m] = acc;
    }
  }
}

// ---- OMP main: one wave per signal ----
__global__ __launch_bounds__(256) void k_omp(const float* __restrict__ A0,
                                             const float* __restrict__ G,
                                             float4* __restrict__ wg, int4* __restrict__ wi) {
  int tid = threadIdx.x;
  int lane = tid & 63;
  int wv = __builtin_amdgcn_readfirstlane(tid >> 6);
  int n = blockIdx.x * 4 + wv;  // grid = 8192 blocks
  const float4* ap = (const float4*)(A0 + (size_t)n * KDIM + lane * 8);
  float4 v0 = ap[0], v1 = ap[1];
  float a0[8] = {v0.x, v0.y, v0.z, v0.w, v1.x, v1.y, v1.z, v1.w};
  float al[8];
#pragma unroll
  for (int m = 0; m < 8; ++m) al[m] = a0[m];
  float Grow[3][8];
  float gs[4][4];
  float rhs[4];
  int idx[4];
  float gamma[4];
  omp_step<0>(lane, n, G, A0, a0, al, Grow, gs, rhs, idx, gamma);
  omp_step<1>(lane, n, G, A0, a0, al, Grow, gs, rhs, idx, gamma);
  omp_step<2>(lane, n, G, A0, a0, al, Grow, gs, rhs, idx, gamma);
  omp_step<3>(lane, n, G, A0, a0, al, Grow, gs, rhs, idx, gamma);
  // dedupe: scatter-set semantics — later slot with same index wins
  bool k0 = (idx[0] != idx[1]) && (idx[0] != idx[2]) && (idx[0] != idx[3]);
  bool k1 = (idx[1] != idx[2]) && (idx[1] != idx[3]);
  bool k2 = (idx[2] != idx[3]);
  if (lane == 0) {
    wg[n] = make_float4(k0 ? gamma[0] : 0.f, k1 ? gamma[1] : 0.f,
                        k2 ? gamma[2] : 0.f, gamma[3]);
    wi[n] = make_int4(idx[0], idx[1], idx[2], idx[3]);
  }
}

// ---- fused epilogue: blocks 0..511 quant+stats, 512..2559 dense ids;
//      last block (atomic ticket) finalizes the scalars ----
__global__ __launch_bounds__(256) void k_ei(const float* __restrict__ X,
                                            const float* __restrict__ DnT,
                                            const float4* __restrict__ wg,
                                            const int4* __restrict__ wi,
                                            float* __restrict__ out,
                                            double* __restrict__ accs,
                                            int* __restrict__ hist,
                                            int* __restrict__ cnt,
                                            const float* __restrict__ pd) {
  __shared__ __align__(16) int sIdx[64][4];
  __shared__ __align__(16) float sKg[64][4];
  __shared__ float q[64 * 65];
  __shared__ float red[4];
  int tid = threadIdx.x;

  if (blockIdx.x < 512) {
    int bh = blockIdx.x;
    int b = bh >> 6, h = bh & 63;
    if (tid < 64) {
      int w = tid;
      int n = bh * 64 + w;
      int4 iv = wi[n];
      float4 gv = wg[n];  // already deduped in k_omp
      sIdx[w][0] = iv.x; sIdx[w][1] = iv.y; sIdx[w][2] = iv.z; sIdx[w][3] = iv.w;
      sKg[w][0] = gv.x; sKg[w][1] = gv.y; sKg[w][2] = gv.z; sKg[w][3] = gv.w;
      int nz = (int)(gv.x != 0.f) + (int)(gv.y != 0.f) +
               (int)(gv.z != 0.f) + (int)(gv.w != 0.f);
      float s = fabsf(gv.x) + fabsf(gv.y) + fabsf(gv.z) + fabsf(gv.w);
#pragma unroll
      for (int off = 32; off >= 1; off >>= 1) s += __shfl_xor(s, off);
#pragma unroll
      for (int v = 0; v < 5; ++v) {
        unsigned long long m = __ballot(nz == v);
        if (tid == 0) {
          int c = (int)__popcll(m);
          if (c) atomicAdd(&hist[v], c);
        }
      }
      if (tid == 0) atomicAdd(&accs[0], (double)s);
    }
    __syncthreads();

    int w2 = tid & 63, p = tid >> 6, c0 = p * 16;
    float acc[16] = {};
#pragma unroll
    for (int s = 0; s < 4; ++s) {
      int ks = sIdx[w2][s];
      float g = sKg[w2][s];
      const float4* dp = (const float4*)(DnT + (size_t)ks * CDIM + c0);
#pragma unroll
      for (int i4 = 0; i4 < 4; ++i4) {
        float4 d = dp[i4];
        acc[i4 * 4 + 0] = fmaf(g, d.x, acc[i4 * 4 + 0]);
        acc[i4 * 4 + 1] = fmaf(g, d.y, acc[i4 * 4 + 1]);
        acc[i4 * 4 + 2] = fmaf(g, d.z, acc[i4 * 4 + 2]);
        acc[i4 * 4 + 3] = fmaf(g, d.w, acc[i4 * 4 + 3]);
      }
    }
#pragma unroll
    for (int i = 0; i < 16; ++i) q[(c0 + i) * 65 + w2] = acc[i];
    __syncthreads();

    float sumsq = 0.f;
#pragma unroll
    for (int pass = 0; pass < 16; ++pass) {
      int c = pass * 4 + p;
      float qv = q[c * 65 + w2];
      size_t off = (((size_t)b * CDIM + c) * HQ + h) * WQ + w2;
      float xv = X[off];
      float d = qv - xv;
      sumsq = fmaf(d, d, sumsq);
      out[off] = qv;
    }

#pragma unroll
    for (int off = 32; off >= 1; off >>= 1) sumsq += __shfl_xor(sumsq, off);
    if ((tid & 63) == 0) red[tid >> 6] = sumsq;
    __syncthreads();
    if (tid == 0) atomicAdd(&accs[1], (double)(red[0] + red[1] + red[2] + red[3]));
  } else {
    // ---------------- dense ids write (dwordx4, 4 signals/thread) ----------------
    int bid = blockIdx.x - 512;
    int bh = bid >> 2, kq = bid & 3;
    int b = bh >> 6, h = bh & 63;
    if (tid < 64) {
      int n = bh * 64 + tid;
      *(int4*)&sIdx[tid][0] = wi[n];
      *(float4*)&sKg[tid][0] = wg[n];
    }
    __syncthreads();
    int w4 = (tid & 15) * 4, kl = tid >> 4;
    int4 I0 = *(const int4*)&sIdx[w4][0];
    int4 I1 = *(const int4*)&sIdx[w4 + 1][0];
    int4 I2 = *(const int4*)&sIdx[w4 + 2][0];
    int4 I3 = *(const int4*)&sIdx[w4 + 3][0];
    float4 G0 = *(const float4*)&sKg[w4][0];
    float4 G1 = *(const float4*)&sKg[w4 + 1][0];
    float4 G2 = *(const float4*)&sKg[w4 + 2][0];
    float4 G3 = *(const float4*)&sKg[w4 + 3][0];
    float* ids = out + IDS_OFF;
    size_t base = (((size_t)b * KDIM + kq * 128 + kl) * HQ + h) * WQ + w4;
#pragma unroll
    for (int pass = 0; pass < 8; ++pass) {
      int k = kq * 128 + pass * 16 + kl;
      // reverse-order select chain = scatter last-wins semantics
      float4 v;
      v.x = (k == I0.w) ? G0.w : (k == I0.z) ? G0.z : (k == I0.y) ? G0.y : (k == I0.x) ? G0.x : 0.f;
      v.y = (k == I1.w) ? G1.w : (k == I1.z) ? G1.z : (k == I1.y) ? G1.y : (k == I1.x) ? G1.x : 0.f;
      v.z = (k == I2.w) ? G2.w : (k == I2.z) ? G2.z : (k == I2.y) ? G2.y : (k == I2.x) ? G2.x : 0.f;
      v.w = (k == I3.w) ? G3.w : (k == I3.z) ? G3.z : (k == I3.y) ? G3.y : (k == I3.x) ? G3.x : 0.f;
      *(float4*)&ids[base + (size_t)pass * 16 * 4096] = v;
    }
  }

  // ---- last-block finalize ----
  __threadfence();
  if (tid == 0) {
    int old = atomicAdd(cnt, 1);
    if (old == 2559) {
      float sumAbsD = 0.f;
#pragma unroll
      for (int i = 0; i < 8; ++i) sumAbsD += pd[i];
      double sumAbsZ = atomicAdd(&accs[0], 0.0);
      double sumSq = atomicAdd(&accs[1], 0.0);
      int h0 = atomicAdd(&hist[0], 0), h1 = atomicAdd(&hist[1], 0);
      int h2 = atomicAdd(&hist[2], 0), h3 = atomicAdd(&hist[3], 0);
      int h4 = atomicAdd(&hist[4], 0);
      float diff = (float)(sumSq / 2097152.0);
      out[DIFF_ENC_OFF] = diff;
      out[DIFF_DICT_OFF] = diff;
      out[NUM_STEPS_OFF] = 4.0f;
      out[MEAN_D_OFF] = sumAbsD / 32768.0f;
      out[MEAN_Z_OFF] = (float)(sumAbsZ / 16777216.0);
      out[NORM_Z_OFF] = (float)((double)(h1 + 2 * h2 + 3 * h3 + 4 * h4) / 32768.0);
      int cum = 0, res = 0;
      for (int v = 4; v >= 0; --v) {
        cum += hist[v];
        if (cum >= 327) { res = v; break; }
      }
      out[TOP_PCT_OFF] = (float)res;
      out[NUM_ZEROS_OFF] = (float)h0;
    }
  }
}

extern "C" void kernel_launch(void* const* d_in, const int* in_sizes, int n_in,
                              void* d_out, int out_size, void* d_ws, size_t ws_size,
                              hipStream_t stream) {
  (void)in_sizes; (void)n_in; (void)out_size; (void)ws_size;
  const float* X = (const float*)d_in[0];    // [8,64,64,64]
  const float* D = (const float*)d_in[1];    // [64,512]
  float* out = (float*)d_out;
  float* W = (float*)d_ws;
  double* accs = (double*)d_ws;
  int* hist = (int*)W + 4;
  int* cnt = (int*)W + 9;
  float* pd = W + WS_PD;
  float* DnT = W + WS_DNT;
  float* G = W + WS_G;
  float4* wgam = (float4*)(W + WS_WG);
  int4* widx = (int4*)(W + WS_WI);
  float* A0 = out;  // stage alpha0 in d_out[0 .. 16,777,216) — overwritten later

  hipLaunchKernelGGL(k_ga, dim3(4160), dim3(256), 0, stream, X, D, A0, G, DnT, pd, W);
  hipLaunchKernelGGL(k_omp, dim3(8192), dim3(256), 0, stream, A0, G, wgam, widx);
  hipLaunchKernelGGL(k_ei, dim3(2560), dim3(256), 0, stream, X, DnT, wgam, widx, out,
                     accs, hist, cnt, pd);
}

// Round 6
// 172.651 us; speedup vs baseline: 3.0304x; 3.0304x over previous
//
#include <hip/hip_runtime.h>
#include <cstdint>
#include <cstddef>

// Problem constants
#define BQ 8
#define CDIM 64
#define HQ 64
#define WQ 64
#define KDIM 512
#define N_SIG 32768   // B*H*W
#define S_NNZ 4

// d_out float offsets (outputs concatenated flat in return order)
#define DIFF_ENC_OFF 2097152
#define DIFF_DICT_OFF 2097153
#define IDS_OFF 2097154
#define NUM_STEPS_OFF 18874370
#define MEAN_D_OFF 18874371
#define MEAN_Z_OFF 18874372
#define NORM_Z_OFF 18874373
#define TOP_PCT_OFF 18874374
#define NUM_ZEROS_OFF 18874375

// ws float-offsets
// words [0..3]  : accs[2] doubles: sumAbsZ, sumSq (zeroed by k_ga block 0)
// words [4..8]  : hist[5] ints                    (zeroed by k_ga block 0)
// [16..24)      : pd[8] per-diagonal-block |Dn| partial sums
#define WS_PD 16
#define WS_DNT 24
#define WS_G 32792
#define WS_WG 294936   // float4 per signal (deduped gamma)
#define WS_WI 426008   // int4 per signal (idx)

typedef float v2f __attribute__((ext_vector_type(2)));

// ---- fused GEMM, self-normalizing (NO device fences anywhere):
//   blocks 0..63    : G = Dn^T Dn (8x8 tiles of 64); diagonal blocks also emit DnT + pd
//   blocks 64..4159 : alpha0 = X @ Dn (512 bh-tiles x 8 n-tiles)
__global__ __launch_bounds__(256) void k_ga(const float* __restrict__ X,
                                            const float* __restrict__ D,
                                            float* __restrict__ A0,
                                            float* __restrict__ G,
                                            float* __restrict__ DnT,
                                            float* __restrict__ pd,
                                            float* __restrict__ W) {
  __shared__ float Xs[64 * 65];
  __shared__ float Dns[64 * 64];
  __shared__ float partA[4][64];
  __shared__ float partB[4][64];
  __shared__ float invA[64];
  __shared__ float invB[64];
  int tid = threadIdx.x;
  int w = tid & 63, cq = tid >> 6;
  int ty = tid >> 4, tx = tid & 15;
  if (blockIdx.x == 0 && tid < 16) ((unsigned int*)W)[tid] = 0u;  // accs+hist zero

  if (blockIdx.x < 64) {
    // ---------------- Gram tile (ti,tj) of 64x64 ----------------
    int ti = (int)blockIdx.x >> 3, tj = (int)blockIdx.x & 7;
#pragma unroll
    for (int p = 0; p < 16; ++p) {
      int c = p * 4 + cq;
      Xs[c * 64 + w] = D[(size_t)c * KDIM + ti * 64 + w];
      Dns[c * 64 + w] = D[(size_t)c * KDIM + tj * 64 + w];
    }
    __syncthreads();
    // column norms of both tiles (4 partials per column)
    float ssA = 0.f, ssB = 0.f;
#pragma unroll
    for (int cc = 0; cc < 16; ++cc) {
      int c = cq * 16 + cc;
      float a = Xs[c * 64 + w];
      ssA = fmaf(a, a, ssA);
      float bv = Dns[c * 64 + w];
      ssB = fmaf(bv, bv, ssB);
    }
    partA[cq][w] = ssA;
    partB[cq][w] = ssB;
    __syncthreads();
    if (tid < 64) {
      invA[tid] = 1.0f / sqrtf(partA[0][tid] + partA[1][tid] + partA[2][tid] + partA[3][tid]);
      invB[tid] = 1.0f / sqrtf(partB[0][tid] + partB[1][tid] + partB[2][tid] + partB[3][tid]);
    }
    __syncthreads();
    if (ti == tj) {
      // emit normalized DnT rows ti*64..+63 and pd[ti] = sum|Dn| partial
      int kl = tid >> 2, cp = (tid & 3) * 16;
      float ia = invA[kl];
      float sabs = 0.f;
#pragma unroll
      for (int i = 0; i < 16; ++i) {
        int c = cp + i;
        float v = Xs[c * 64 + kl] * ia;
        DnT[(size_t)(ti * 64 + kl) * CDIM + c] = v;
        sabs += fabsf(v);
      }
#pragma unroll
      for (int off = 32; off >= 1; off >>= 1) sabs += __shfl_xor(sabs, off);
      __syncthreads();
      if ((tid & 63) == 0) partA[0][tid >> 6] = sabs;
      __syncthreads();
      if (tid == 0) pd[ti] = partA[0][0] + partA[0][1] + partA[0][2] + partA[0][3];
    }
    // gram main loop on raw tiles
    v2f acc[4][2] = {};
    for (int c = 0; c < 64; ++c) {
      float4 avv = *(const float4*)&Xs[c * 64 + ty * 4];
      float av[4] = {avv.x, avv.y, avv.z, avv.w};
      float4 bv = *(const float4*)&Dns[c * 64 + tx * 4];
      v2f b0 = {bv.x, bv.y}, b1 = {bv.z, bv.w};
#pragma unroll
      for (int i = 0; i < 4; ++i) {
        v2f a2 = {av[i], av[i]};
        acc[i][0] = __builtin_elementwise_fma(a2, b0, acc[i][0]);
        acc[i][1] = __builtin_elementwise_fma(a2, b1, acc[i][1]);
      }
    }
    float sn[4] = {invB[tx * 4], invB[tx * 4 + 1], invB[tx * 4 + 2], invB[tx * 4 + 3]};
#pragma unroll
    for (int i = 0; i < 4; ++i) {
      float im = invA[ty * 4 + i];
      float4 st = make_float4(acc[i][0].x * im * sn[0], acc[i][0].y * im * sn[1],
                              acc[i][1].x * im * sn[2], acc[i][1].y * im * sn[3]);
      *(float4*)&G[(size_t)(ti * 64 + ty * 4 + i) * KDIM + tj * 64 + tx * 4] = st;
    }
  } else {
    // ---------------- alpha0 tile: 64 signals x 64 atoms ----------------
    int bb = (int)blockIdx.x - 64;
    int mt = bb >> 3, nt = bb & 7;
    int b = mt >> 6, h = mt & 63;
#pragma unroll
    for (int p = 0; p < 16; ++p) {
      int c = p * 4 + cq;
      Xs[w * 65 + c] = X[(((size_t)b * CDIM + c) * HQ + h) * WQ + w];
      Dns[c * 64 + w] = D[(size_t)c * KDIM + nt * 64 + w];
    }
    __syncthreads();
    float ssB = 0.f;
#pragma unroll
    for (int cc = 0; cc < 16; ++cc) {
      int c = cq * 16 + cc;
      float bv = Dns[c * 64 + w];
      ssB = fmaf(bv, bv, ssB);
    }
    partB[cq][w] = ssB;
    __syncthreads();
    if (tid < 64)
      invB[tid] = 1.0f / sqrtf(partB[0][tid] + partB[1][tid] + partB[2][tid] + partB[3][tid]);
    __syncthreads();
    v2f acc[4][2] = {};
    for (int c = 0; c < 64; ++c) {
      float av[4];
#pragma unroll
      for (int i = 0; i < 4; ++i) av[i] = Xs[(ty * 4 + i) * 65 + c];
      float4 bv = *(const float4*)&Dns[c * 64 + tx * 4];
      v2f b0 = {bv.x, bv.y}, b1 = {bv.z, bv.w};
#pragma unroll
      for (int i = 0; i < 4; ++i) {
        v2f a2 = {av[i], av[i]};
        acc[i][0] = __builtin_elementwise_fma(a2, b0, acc[i][0]);
        acc[i][1] = __builtin_elementwise_fma(a2, b1, acc[i][1]);
      }
    }
    float sn[4] = {invB[tx * 4], invB[tx * 4 + 1], invB[tx * 4 + 2], invB[tx * 4 + 3]};
    size_t n0 = (size_t)mt * 64;
#pragma unroll
    for (int i = 0; i < 4; ++i) {
      float4 st = make_float4(acc[i][0].x * sn[0], acc[i][0].y * sn[1],
                              acc[i][1].x * sn[2], acc[i][1].y * sn[3]);
      *(float4*)&A0[(n0 + ty * 4 + i) * KDIM + nt * 64 + tx * 4] = st;
    }
  }
}

// ---- fp32 solve, no pivoting (G_II near-identity), saved reciprocals ----
template <int SZ>
__device__ __forceinline__ void solve_sz(const float (&gs)[4][4], const float (&rhs)[4],
                                         float (&gamma)[4]) {
  float M[SZ][SZ];
  float y[SZ];
  float idg[SZ];
#pragma unroll
  for (int a = 0; a < SZ; ++a) {
    y[a] = rhs[a];
#pragma unroll
    for (int b = 0; b < SZ; ++b) M[a][b] = gs[a][b] + (a == b ? 1e-7f : 0.0f);
  }
#pragma unroll
  for (int p = 0; p < SZ; ++p) {
    float ip = __builtin_amdgcn_rcpf(M[p][p]);
    idg[p] = ip;
#pragma unroll
    for (int r = p + 1; r < SZ; ++r) {
      float f = M[r][p] * ip;
#pragma unroll
      for (int c = p + 1; c < SZ; ++c) M[r][c] = fmaf(-f, M[p][c], M[r][c]);
      y[r] = fmaf(-f, y[p], y[r]);
    }
  }
#pragma unroll
  for (int r = SZ - 1; r >= 0; --r) {
    float t = y[r];
#pragma unroll
    for (int c = r + 1; c < SZ; ++c) t = fmaf(-M[r][c], gamma[c], t);
    gamma[r] = t * idg[r];
  }
}

template <int K>
__device__ __forceinline__ void omp_step(int lane, int n, const float* __restrict__ G,
                                         const float* __restrict__ A0,
                                         float (&a0)[8], float (&al)[8], float (&Grow)[3][8],
                                         float (&gs)[4][4], float (&rhs)[4], int (&idx)[4],
                                         float (&gamma)[4]) {
  // argmax |al| over 512, first-occurrence (lowest k) wins
  float mx = fabsf(al[0]);
#pragma unroll
  for (int m = 1; m < 8; ++m) mx = fmaxf(mx, fabsf(al[m]));
#pragma unroll
  for (int off = 32; off >= 1; off >>= 1) mx = fmaxf(mx, __shfl_xor(mx, off));
  int sk = 1 << 30;
#pragma unroll
  for (int m = 0; m < 8; ++m) {
    unsigned long long bm = __ballot(fabsf(al[m]) == mx);
    if (bm) {
      int kk = (int)__builtin_ctzll(bm) * 8 + m;
      sk = kk < sk ? kk : sk;
    }
  }
  idx[K] = sk;  // wave-uniform (derived from ballots)

  const float* grow_base = G + (size_t)sk * KDIM;
  if constexpr (K < 3) {
    const float4* gp = (const float4*)(grow_base + lane * 8);
    float4 r0 = gp[0], r1 = gp[1];
    Grow[K][0] = r0.x; Grow[K][1] = r0.y; Grow[K][2] = r0.z; Grow[K][3] = r0.w;
    Grow[K][4] = r1.x; Grow[K][5] = r1.y; Grow[K][6] = r1.z; Grow[K][7] = r1.w;
  }

#pragma unroll
  for (int b = 0; b < K; ++b) {
    float v = grow_base[idx[b]];
    gs[K][b] = v;
    gs[b][K] = v;
  }
  gs[K][K] = grow_base[sk];
  rhs[K] = A0[(size_t)n * KDIM + sk];

  solve_sz<K + 1>(gs, rhs, gamma);

  if constexpr (K < 3) {
#pragma unroll
    for (int m = 0; m < 8; ++m) {
      float acc = a0[m];
#pragma unroll
      for (int a = 0; a <= K; ++a) acc = fmaf(-gamma[a], Grow[a][m], acc);
      al[m] = acc;
    }
  }
}

// ---- OMP main: one wave per signal ----
__global__ __launch_bounds__(256) void k_omp(const float* __restrict__ A0,
                                             const float* __restrict__ G,
                                             float4* __restrict__ wg, int4* __restrict__ wi) {
  int tid = threadIdx.x;
  int lane = tid & 63;
  int wv = __builtin_amdgcn_readfirstlane(tid >> 6);
  int n = blockIdx.x * 4 + wv;  // grid = 8192 blocks
  const float4* ap = (const float4*)(A0 + (size_t)n * KDIM + lane * 8);
  float4 v0 = ap[0], v1 = ap[1];
  float a0[8] = {v0.x, v0.y, v0.z, v0.w, v1.x, v1.y, v1.z, v1.w};
  float al[8];
#pragma unroll
  for (int m = 0; m < 8; ++m) al[m] = a0[m];
  float Grow[3][8];
  float gs[4][4];
  float rhs[4];
  int idx[4];
  float gamma[4];
  omp_step<0>(lane, n, G, A0, a0, al, Grow, gs, rhs, idx, gamma);
  omp_step<1>(lane, n, G, A0, a0, al, Grow, gs, rhs, idx, gamma);
  omp_step<2>(lane, n, G, A0, a0, al, Grow, gs, rhs, idx, gamma);
  omp_step<3>(lane, n, G, A0, a0, al, Grow, gs, rhs, idx, gamma);
  // dedupe: scatter-set semantics — later slot with same index wins
  bool k0 = (idx[0] != idx[1]) && (idx[0] != idx[2]) && (idx[0] != idx[3]);
  bool k1 = (idx[1] != idx[2]) && (idx[1] != idx[3]);
  bool k2 = (idx[2] != idx[3]);
  if (lane == 0) {
    wg[n] = make_float4(k0 ? gamma[0] : 0.f, k1 ? gamma[1] : 0.f,
                        k2 ? gamma[2] : 0.f, gamma[3]);
    wi[n] = make_int4(idx[0], idx[1], idx[2], idx[3]);
  }
}

// ---- fused epilogue: blocks 0..511 quant+stats, 512..2559 dense ids ----
__global__ __launch_bounds__(256) void k_ei(const float* __restrict__ X,
                                            const float* __restrict__ DnT,
                                            const float4* __restrict__ wg,
                                            const int4* __restrict__ wi,
                                            float* __restrict__ out,
                                            double* __restrict__ accs,
                                            int* __restrict__ hist) {
  __shared__ __align__(16) int sIdx[64][4];
  __shared__ __align__(16) float sKg[64][4];
  __shared__ float q[64 * 65];
  __shared__ float red[4];
  int tid = threadIdx.x;

  if (blockIdx.x < 512) {
    int bh = blockIdx.x;
    int b = bh >> 6, h = bh & 63;
    if (tid < 64) {
      int w = tid;
      int n = bh * 64 + w;
      int4 iv = wi[n];
      float4 gv = wg[n];  // already deduped in k_omp
      sIdx[w][0] = iv.x; sIdx[w][1] = iv.y; sIdx[w][2] = iv.z; sIdx[w][3] = iv.w;
      sKg[w][0] = gv.x; sKg[w][1] = gv.y; sKg[w][2] = gv.z; sKg[w][3] = gv.w;
      int nz = (int)(gv.x != 0.f) + (int)(gv.y != 0.f) +
               (int)(gv.z != 0.f) + (int)(gv.w != 0.f);
      float s = fabsf(gv.x) + fabsf(gv.y) + fabsf(gv.z) + fabsf(gv.w);
#pragma unroll
      for (int off = 32; off >= 1; off >>= 1) s += __shfl_xor(s, off);
#pragma unroll
      for (int v = 0; v < 5; ++v) {
        unsigned long long m = __ballot(nz == v);
        if (tid == 0) {
          int c = (int)__popcll(m);
          if (c) atomicAdd(&hist[v], c);
        }
      }
      if (tid == 0) atomicAdd(&accs[0], (double)s);
    }
    __syncthreads();

    int w2 = tid & 63, p = tid >> 6, c0 = p * 16;
    float acc[16] = {};
#pragma unroll
    for (int s = 0; s < 4; ++s) {
      int ks = sIdx[w2][s];
      float g = sKg[w2][s];
      const float4* dp = (const float4*)(DnT + (size_t)ks * CDIM + c0);
#pragma unroll
      for (int i4 = 0; i4 < 4; ++i4) {
        float4 d = dp[i4];
        acc[i4 * 4 + 0] = fmaf(g, d.x, acc[i4 * 4 + 0]);
        acc[i4 * 4 + 1] = fmaf(g, d.y, acc[i4 * 4 + 1]);
        acc[i4 * 4 + 2] = fmaf(g, d.z, acc[i4 * 4 + 2]);
        acc[i4 * 4 + 3] = fmaf(g, d.w, acc[i4 * 4 + 3]);
      }
    }
#pragma unroll
    for (int i = 0; i < 16; ++i) q[(c0 + i) * 65 + w2] = acc[i];
    __syncthreads();

    float sumsq = 0.f;
#pragma unroll
    for (int pass = 0; pass < 16; ++pass) {
      int c = pass * 4 + p;
      float qv = q[c * 65 + w2];
      size_t off = (((size_t)b * CDIM + c) * HQ + h) * WQ + w2;
      float xv = X[off];
      float d = qv - xv;
      sumsq = fmaf(d, d, sumsq);
      out[off] = qv;
    }

#pragma unroll
    for (int off = 32; off >= 1; off >>= 1) sumsq += __shfl_xor(sumsq, off);
    if ((tid & 63) == 0) red[tid >> 6] = sumsq;
    __syncthreads();
    if (tid == 0) atomicAdd(&accs[1], (double)(red[0] + red[1] + red[2] + red[3]));
  } else {
    // ---------------- dense ids write (dwordx4, 4 signals/thread) ----------------
    int bid = blockIdx.x - 512;
    int bh = bid >> 2, kq = bid & 3;
    int b = bh >> 6, h = bh & 63;
    if (tid < 64) {
      int n = bh * 64 + tid;
      *(int4*)&sIdx[tid][0] = wi[n];
      *(float4*)&sKg[tid][0] = wg[n];
    }
    __syncthreads();
    int w4 = (tid & 15) * 4, kl = tid >> 4;
    int4 I0 = *(const int4*)&sIdx[w4][0];
    int4 I1 = *(const int4*)&sIdx[w4 + 1][0];
    int4 I2 = *(const int4*)&sIdx[w4 + 2][0];
    int4 I3 = *(const int4*)&sIdx[w4 + 3][0];
    float4 G0 = *(const float4*)&sKg[w4][0];
    float4 G1 = *(const float4*)&sKg[w4 + 1][0];
    float4 G2 = *(const float4*)&sKg[w4 + 2][0];
    float4 G3 = *(const float4*)&sKg[w4 + 3][0];
    float* ids = out + IDS_OFF;
    size_t base = (((size_t)b * KDIM + kq * 128 + kl) * HQ + h) * WQ + w4;
#pragma unroll
    for (int pass = 0; pass < 8; ++pass) {
      int k = kq * 128 + pass * 16 + kl;
      // reverse-order select chain = scatter last-wins semantics
      float4 v;
      v.x = (k == I0.w) ? G0.w : (k == I0.z) ? G0.z : (k == I0.y) ? G0.y : (k == I0.x) ? G0.x : 0.f;
      v.y = (k == I1.w) ? G1.w : (k == I1.z) ? G1.z : (k == I1.y) ? G1.y : (k == I1.x) ? G1.x : 0.f;
      v.z = (k == I2.w) ? G2.w : (k == I2.z) ? G2.z : (k == I2.y) ? G2.y : (k == I2.x) ? G2.x : 0.f;
      v.w = (k == I3.w) ? G3.w : (k == I3.z) ? G3.z : (k == I3.y) ? G3.y : (k == I3.x) ? G3.x : 0.f;
      *(float4*)&ids[base + (size_t)pass * 16 * 4096] = v;
    }
  }
}

// ---- finalize scalars (separate 1-block dispatch; stream order = no fence needed) ----
__global__ __launch_bounds__(64) void k_final(const double* __restrict__ accs,
                                              const int* __restrict__ hist,
                                              const float* __restrict__ pd,
                                              float* __restrict__ out) {
  if (threadIdx.x == 0) {
    float sumAbsD = 0.f;
#pragma unroll
    for (int i = 0; i < 8; ++i) sumAbsD += pd[i];
    double sumAbsZ = accs[0], sumSq = accs[1];
    float diff = (float)(sumSq / 2097152.0);
    out[DIFF_ENC_OFF] = diff;
    out[DIFF_DICT_OFF] = diff;
    out[NUM_STEPS_OFF] = 4.0f;
    out[MEAN_D_OFF] = sumAbsD / 32768.0f;
    out[MEAN_Z_OFF] = (float)(sumAbsZ / 16777216.0);
    int h0 = hist[0], h1 = hist[1], h2 = hist[2], h3 = hist[3], h4 = hist[4];
    out[NORM_Z_OFF] = (float)((double)(h1 + 2 * h2 + 3 * h3 + 4 * h4) / 32768.0);
    int cum = 0, res = 0;
    for (int v = 4; v >= 0; --v) {
      cum += hist[v];
      if (cum >= 327) { res = v; break; }
    }
    out[TOP_PCT_OFF] = (float)res;
    out[NUM_ZEROS_OFF] = (float)h0;
  }
}

extern "C" void kernel_launch(void* const* d_in, const int* in_sizes, int n_in,
                              void* d_out, int out_size, void* d_ws, size_t ws_size,
                              hipStream_t stream) {
  (void)in_sizes; (void)n_in; (void)out_size; (void)ws_size;
  const float* X = (const float*)d_in[0];    // [8,64,64,64]
  const float* D = (const float*)d_in[1];    // [64,512]
  float* out = (float*)d_out;
  float* W = (float*)d_ws;
  double* accs = (double*)d_ws;
  int* hist = (int*)W + 4;
  float* pd = W + WS_PD;
  float* DnT = W + WS_DNT;
  float* G = W + WS_G;
  float4* wgam = (float4*)(W + WS_WG);
  int4* widx = (int4*)(W + WS_WI);
  float* A0 = out;  // stage alpha0 in d_out[0 .. 16,777,216) — overwritten later

  hipLaunchKernelGGL(k_ga, dim3(4160), dim3(256), 0, stream, X, D, A0, G, DnT, pd, W);
  hipLaunchKernelGGL(k_omp, dim3(8192), dim3(256), 0, stream, A0, G, wgam, widx);
  hipLaunchKernelGGL(k_ei, dim3(2560), dim3(256), 0, stream, X, DnT, wgam, widx, out, accs, hist);
  hipLaunchKernelGGL(k_final, dim3(1), dim3(64), 0, stream, accs, hist, pd, out);
}

// Round 7
// 169.560 us; speedup vs baseline: 3.0856x; 1.0182x over previous
//
#include <hip/hip_runtime.h>
#include <cstdint>
#include <cstddef>

// Problem constants
#define BQ 8
#define CDIM 64
#define HQ 64
#define WQ 64
#define KDIM 512
#define N_SIG 32768   // B*H*W
#define S_NNZ 4

// d_out float offsets (outputs concatenated flat in return order)
#define DIFF_ENC_OFF 2097152
#define DIFF_DICT_OFF 2097153
#define IDS_OFF 2097154
#define NUM_STEPS_OFF 18874370
#define MEAN_D_OFF 18874371
#define MEAN_Z_OFF 18874372
#define NORM_Z_OFF 18874373
#define TOP_PCT_OFF 18874374
#define NUM_ZEROS_OFF 18874375

// ws float-offsets
// words [0..3]  : accs[2] doubles: sumAbsZ, sumSq (zeroed by k_ga block 0)
// words [4..8]  : hist[5] ints                    (zeroed by k_ga block 0)
// [16..24)      : pd[8] per-diagonal-block |Dn| partial sums
#define WS_PD 16
#define WS_DNT 24
#define WS_G 32792
#define WS_WG 294936   // float4 per signal (deduped gamma)
#define WS_WI 426008   // int4 per signal (idx)

typedef float v2f __attribute__((ext_vector_type(2)));

// ---- fused GEMM, self-normalizing:
//   blocks 0..63    : G = Dn^T Dn (8x8 tiles of 64); diagonal blocks also emit DnT + pd
//   blocks 64..4159 : alpha0 = X @ Dn (512 bh-tiles x 8 n-tiles)
// Both paths use c-major unpadded LDS tiles -> all compute reads are ds_read_b128.
__global__ __launch_bounds__(256) void k_ga(const float* __restrict__ X,
                                            const float* __restrict__ D,
                                            float* __restrict__ A0,
                                            float* __restrict__ G,
                                            float* __restrict__ DnT,
                                            float* __restrict__ pd,
                                            float* __restrict__ W) {
  __shared__ float Xs[64 * 64];
  __shared__ float Dns[64 * 64];
  __shared__ float partA[4][64];
  __shared__ float partB[4][64];
  __shared__ float invA[64];
  __shared__ float invB[64];
  int tid = threadIdx.x;
  int w = tid & 63, cq = tid >> 6;
  int ty = tid >> 4, tx = tid & 15;
  if (blockIdx.x == 0 && tid < 16) ((unsigned int*)W)[tid] = 0u;  // accs+hist zero

  if (blockIdx.x < 64) {
    // ---------------- Gram tile (ti,tj) of 64x64 ----------------
    int ti = (int)blockIdx.x >> 3, tj = (int)blockIdx.x & 7;
#pragma unroll
    for (int p = 0; p < 16; ++p) {
      int c = p * 4 + cq;
      Xs[c * 64 + w] = D[(size_t)c * KDIM + ti * 64 + w];
      Dns[c * 64 + w] = D[(size_t)c * KDIM + tj * 64 + w];
    }
    __syncthreads();
    float ssA = 0.f, ssB = 0.f;
#pragma unroll
    for (int cc = 0; cc < 16; ++cc) {
      int c = cq * 16 + cc;
      float a = Xs[c * 64 + w];
      ssA = fmaf(a, a, ssA);
      float bv = Dns[c * 64 + w];
      ssB = fmaf(bv, bv, ssB);
    }
    partA[cq][w] = ssA;
    partB[cq][w] = ssB;
    __syncthreads();
    if (tid < 64) {
      invA[tid] = 1.0f / sqrtf(partA[0][tid] + partA[1][tid] + partA[2][tid] + partA[3][tid]);
      invB[tid] = 1.0f / sqrtf(partB[0][tid] + partB[1][tid] + partB[2][tid] + partB[3][tid]);
    }
    __syncthreads();
    if (ti == tj) {
      // emit normalized DnT rows ti*64..+63 and pd[ti] = sum|Dn| partial
      int kl = tid >> 2, cp = (tid & 3) * 16;
      float ia = invA[kl];
      float sabs = 0.f;
#pragma unroll
      for (int i = 0; i < 16; ++i) {
        int c = cp + i;
        float v = Xs[c * 64 + kl] * ia;
        DnT[(size_t)(ti * 64 + kl) * CDIM + c] = v;
        sabs += fabsf(v);
      }
#pragma unroll
      for (int off = 32; off >= 1; off >>= 1) sabs += __shfl_xor(sabs, off);
      __syncthreads();
      if ((tid & 63) == 0) partA[0][tid >> 6] = sabs;
      __syncthreads();
      if (tid == 0) pd[ti] = partA[0][0] + partA[0][1] + partA[0][2] + partA[0][3];
    }
    v2f acc[4][2] = {};
    for (int c = 0; c < 64; ++c) {
      float4 avv = *(const float4*)&Xs[c * 64 + ty * 4];
      float av[4] = {avv.x, avv.y, avv.z, avv.w};
      float4 bv = *(const float4*)&Dns[c * 64 + tx * 4];
      v2f b0 = {bv.x, bv.y}, b1 = {bv.z, bv.w};
#pragma unroll
      for (int i = 0; i < 4; ++i) {
        v2f a2 = {av[i], av[i]};
        acc[i][0] = __builtin_elementwise_fma(a2, b0, acc[i][0]);
        acc[i][1] = __builtin_elementwise_fma(a2, b1, acc[i][1]);
      }
    }
    float sn[4] = {invB[tx * 4], invB[tx * 4 + 1], invB[tx * 4 + 2], invB[tx * 4 + 3]};
#pragma unroll
    for (int i = 0; i < 4; ++i) {
      float im = invA[ty * 4 + i];
      float4 st = make_float4(acc[i][0].x * im * sn[0], acc[i][0].y * im * sn[1],
                              acc[i][1].x * im * sn[2], acc[i][1].y * im * sn[3]);
      *(float4*)&G[(size_t)(ti * 64 + ty * 4 + i) * KDIM + tj * 64 + tx * 4] = st;
    }
  } else {
    // ---------------- alpha0 tile: 64 signals x 64 atoms (c-major Xs) ----------------
    int bb = (int)blockIdx.x - 64;
    int mt = bb >> 3, nt = bb & 7;
    int b = mt >> 6, h = mt & 63;
#pragma unroll
    for (int p = 0; p < 16; ++p) {
      int c = p * 4 + cq;
      Xs[c * 64 + w] = X[(((size_t)b * CDIM + c) * HQ + h) * WQ + w];
      Dns[c * 64 + w] = D[(size_t)c * KDIM + nt * 64 + w];
    }
    __syncthreads();
    float ssB = 0.f;
#pragma unroll
    for (int cc = 0; cc < 16; ++cc) {
      int c = cq * 16 + cc;
      float bv = Dns[c * 64 + w];
      ssB = fmaf(bv, bv, ssB);
    }
    partB[cq][w] = ssB;
    __syncthreads();
    if (tid < 64)
      invB[tid] = 1.0f / sqrtf(partB[0][tid] + partB[1][tid] + partB[2][tid] + partB[3][tid]);
    __syncthreads();
    v2f acc[4][2] = {};
    for (int c = 0; c < 64; ++c) {
      float4 avv = *(const float4*)&Xs[c * 64 + ty * 4];   // b128, broadcast across tx
      float av[4] = {avv.x, avv.y, avv.z, avv.w};
      float4 bv = *(const float4*)&Dns[c * 64 + tx * 4];   // b128, 2-way (free)
      v2f b0 = {bv.x, bv.y}, b1 = {bv.z, bv.w};
#pragma unroll
      for (int i = 0; i < 4; ++i) {
        v2f a2 = {av[i], av[i]};
        acc[i][0] = __builtin_elementwise_fma(a2, b0, acc[i][0]);
        acc[i][1] = __builtin_elementwise_fma(a2, b1, acc[i][1]);
      }
    }
    float sn[4] = {invB[tx * 4], invB[tx * 4 + 1], invB[tx * 4 + 2], invB[tx * 4 + 3]};
    size_t n0 = (size_t)mt * 64;
#pragma unroll
    for (int i = 0; i < 4; ++i) {
      float4 st = make_float4(acc[i][0].x * sn[0], acc[i][0].y * sn[1],
                              acc[i][1].x * sn[2], acc[i][1].y * sn[3]);
      *(float4*)&A0[(n0 + ty * 4 + i) * KDIM + nt * 64 + tx * 4] = st;
    }
  }
}

// ---- DPP wave-64 max of a non-negative float; returns wave-uniform (SGPR) value ----
__device__ __forceinline__ float wave_absmax_u(float m) {
  // row_shr 1,2,4,8 then row_bcast15, row_bcast31; bound_ctrl=1 -> OOB reads 0,
  // a valid identity for abs values. Exact max, order-invariant.
#define DPP_MAX(ctrl)                                                              \
  {                                                                                \
    int t_ = __builtin_amdgcn_update_dpp(0, __float_as_int(m), (ctrl), 0xf, 0xf,   \
                                         true);                                    \
    m = fmaxf(m, __int_as_float(t_));                                              \
  }
  DPP_MAX(0x111) DPP_MAX(0x112) DPP_MAX(0x114) DPP_MAX(0x118)
  DPP_MAX(0x142) DPP_MAX(0x143)
#undef DPP_MAX
  return __int_as_float(__builtin_amdgcn_readlane(__float_as_int(m), 63));
}

// ---- fp32 solve, no pivoting (G_II near-identity), saved reciprocals ----
template <int SZ>
__device__ __forceinline__ void solve_sz(const float (&gs)[4][4], const float (&rhs)[4],
                                         float (&gamma)[4]) {
  float M[SZ][SZ];
  float y[SZ];
  float idg[SZ];
#pragma unroll
  for (int a = 0; a < SZ; ++a) {
    y[a] = rhs[a];
#pragma unroll
    for (int b = 0; b < SZ; ++b) M[a][b] = gs[a][b] + (a == b ? 1e-7f : 0.0f);
  }
#pragma unroll
  for (int p = 0; p < SZ; ++p) {
    float ip = __builtin_amdgcn_rcpf(M[p][p]);
    idg[p] = ip;
#pragma unroll
    for (int r = p + 1; r < SZ; ++r) {
      float f = M[r][p] * ip;
#pragma unroll
      for (int c = p + 1; c < SZ; ++c) M[r][c] = fmaf(-f, M[p][c], M[r][c]);
      y[r] = fmaf(-f, y[p], y[r]);
    }
  }
#pragma unroll
  for (int r = SZ - 1; r >= 0; --r) {
    float t = y[r];
#pragma unroll
    for (int c = r + 1; c < SZ; ++c) t = fmaf(-M[r][c], gamma[c], t);
    gamma[r] = t * idg[r];
  }
}

template <int K>
__device__ __forceinline__ void omp_step(int lane, int n, const float* __restrict__ G,
                                         const float* __restrict__ A0,
                                         float (&a0)[8], float (&al)[8], float (&Grow)[3][8],
                                         float (&gs)[4][4], float (&rhs)[4], int (&idx)[4],
                                         float (&gamma)[4]) {
  // argmax |al| over 512, first-occurrence (lowest k) wins
  float mx0 = fabsf(al[0]);
#pragma unroll
  for (int m = 1; m < 8; ++m) mx0 = fmaxf(mx0, fabsf(al[m]));
  float mx = wave_absmax_u(mx0);  // wave-uniform SGPR, VALU-latency DPP chain
  int sk = 1 << 30;
#pragma unroll
  for (int m = 0; m < 8; ++m) {
    unsigned long long bm = __ballot(fabsf(al[m]) == mx);
    if (bm) {
      int kk = (int)__builtin_ctzll(bm) * 8 + m;
      sk = kk < sk ? kk : sk;
    }
  }
  idx[K] = sk;  // wave-uniform (derived from ballots)

  const float* grow_base = G + (size_t)sk * KDIM;
  if constexpr (K < 3) {
    const float4* gp = (const float4*)(grow_base + lane * 8);
    float4 r0 = gp[0], r1 = gp[1];
    Grow[K][0] = r0.x; Grow[K][1] = r0.y; Grow[K][2] = r0.z; Grow[K][3] = r0.w;
    Grow[K][4] = r1.x; Grow[K][5] = r1.y; Grow[K][6] = r1.z; Grow[K][7] = r1.w;
  }

#pragma unroll
  for (int b = 0; b < K; ++b) {
    float v = grow_base[idx[b]];
    gs[K][b] = v;
    gs[b][K] = v;
  }
  gs[K][K] = grow_base[sk];
  rhs[K] = A0[(size_t)n * KDIM + sk];

  solve_sz<K + 1>(gs, rhs, gamma);

  if constexpr (K < 3) {
#pragma unroll
    for (int m = 0; m < 8; ++m) {
      float acc = a0[m];
#pragma unroll
      for (int a = 0; a <= K; ++a) acc = fmaf(-gamma[a], Grow[a][m], acc);
      al[m] = acc;
    }
  }
}

// ---- OMP main: one wave per signal ----
__global__ __launch_bounds__(256) void k_omp(const float* __restrict__ A0,
                                             const float* __restrict__ G,
                                             float4* __restrict__ wg, int4* __restrict__ wi) {
  int tid = threadIdx.x;
  int lane = tid & 63;
  int wv = __builtin_amdgcn_readfirstlane(tid >> 6);
  int n = blockIdx.x * 4 + wv;  // grid = 8192 blocks
  const float4* ap = (const float4*)(A0 + (size_t)n * KDIM + lane * 8);
  float4 v0 = ap[0], v1 = ap[1];
  float a0[8] = {v0.x, v0.y, v0.z, v0.w, v1.x, v1.y, v1.z, v1.w};
  float al[8];
#pragma unroll
  for (int m = 0; m < 8; ++m) al[m] = a0[m];
  float Grow[3][8];
  float gs[4][4];
  float rhs[4];
  int idx[4];
  float gamma[4];
  omp_step<0>(lane, n, G, A0, a0, al, Grow, gs, rhs, idx, gamma);
  omp_step<1>(lane, n, G, A0, a0, al, Grow, gs, rhs, idx, gamma);
  omp_step<2>(lane, n, G, A0, a0, al, Grow, gs, rhs, idx, gamma);
  omp_step<3>(lane, n, G, A0, a0, al, Grow, gs, rhs, idx, gamma);
  // dedupe: scatter-set semantics — later slot with same index wins
  bool k0 = (idx[0] != idx[1]) && (idx[0] != idx[2]) && (idx[0] != idx[3]);
  bool k1 = (idx[1] != idx[2]) && (idx[1] != idx[3]);
  bool k2 = (idx[2] != idx[3]);
  if (lane == 0) {
    wg[n] = make_float4(k0 ? gamma[0] : 0.f, k1 ? gamma[1] : 0.f,
                        k2 ? gamma[2] : 0.f, gamma[3]);
    wi[n] = make_int4(idx[0], idx[1], idx[2], idx[3]);
  }
}

// ---- fused epilogue: blocks 0..511 quant+stats, 512..2559 dense ids ----
__global__ __launch_bounds__(256) void k_ei(const float* __restrict__ X,
                                            const float* __restrict__ DnT,
                                            const float4* __restrict__ wg,
                                            const int4* __restrict__ wi,
                                            float* __restrict__ out,
                                            double* __restrict__ accs,
                                            int* __restrict__ hist) {
  __shared__ __align__(16) int sIdx[64][4];
  __shared__ __align__(16) float sKg[64][4];
  __shared__ float q[64 * 65];
  __shared__ float red[4];
  int tid = threadIdx.x;

  if (blockIdx.x < 512) {
    int bh = blockIdx.x;
    int b = bh >> 6, h = bh & 63;
    if (tid < 64) {
      int w = tid;
      int n = bh * 64 + w;
      int4 iv = wi[n];
      float4 gv = wg[n];  // already deduped in k_omp
      sIdx[w][0] = iv.x; sIdx[w][1] = iv.y; sIdx[w][2] = iv.z; sIdx[w][3] = iv.w;
      sKg[w][0] = gv.x; sKg[w][1] = gv.y; sKg[w][2] = gv.z; sKg[w][3] = gv.w;
      int nz = (int)(gv.x != 0.f) + (int)(gv.y != 0.f) +
               (int)(gv.z != 0.f) + (int)(gv.w != 0.f);
      float s = fabsf(gv.x) + fabsf(gv.y) + fabsf(gv.z) + fabsf(gv.w);
#pragma unroll
      for (int off = 32; off >= 1; off >>= 1) s += __shfl_xor(s, off);
#pragma unroll
      for (int v = 0; v < 5; ++v) {
        unsigned long long m = __ballot(nz == v);
        if (tid == 0) {
          int c = (int)__popcll(m);
          if (c) atomicAdd(&hist[v], c);
        }
      }
      if (tid == 0) atomicAdd(&accs[0], (double)s);
    }
    __syncthreads();

    int w2 = tid & 63, p = tid >> 6, c0 = p * 16;
    float acc[16] = {};
#pragma unroll
    for (int s = 0; s < 4; ++s) {
      int ks = sIdx[w2][s];
      float g = sKg[w2][s];
      const float4* dp = (const float4*)(DnT + (size_t)ks * CDIM + c0);
#pragma unroll
      for (int i4 = 0; i4 < 4; ++i4) {
        float4 d = dp[i4];
        acc[i4 * 4 + 0] = fmaf(g, d.x, acc[i4 * 4 + 0]);
        acc[i4 * 4 + 1] = fmaf(g, d.y, acc[i4 * 4 + 1]);
        acc[i4 * 4 + 2] = fmaf(g, d.z, acc[i4 * 4 + 2]);
        acc[i4 * 4 + 3] = fmaf(g, d.w, acc[i4 * 4 + 3]);
      }
    }
#pragma unroll
    for (int i = 0; i < 16; ++i) q[(c0 + i) * 65 + w2] = acc[i];
    __syncthreads();

    float sumsq = 0.f;
#pragma unroll
    for (int pass = 0; pass < 16; ++pass) {
      int c = pass * 4 + p;
      float qv = q[c * 65 + w2];
      size_t off = (((size_t)b * CDIM + c) * HQ + h) * WQ + w2;
      float xv = X[off];
      float d = qv - xv;
      sumsq = fmaf(d, d, sumsq);
      out[off] = qv;
    }

#pragma unroll
    for (int off = 32; off >= 1; off >>= 1) sumsq += __shfl_xor(sumsq, off);
    if ((tid & 63) == 0) red[tid >> 6] = sumsq;
    __syncthreads();
    if (tid == 0) atomicAdd(&accs[1], (double)(red[0] + red[1] + red[2] + red[3]));
  } else {
    // ---------------- dense ids write (dwordx4, 4 signals/thread) ----------------
    int bid = blockIdx.x - 512;
    int bh = bid >> 2, kq = bid & 3;
    int b = bh >> 6, h = bh & 63;
    if (tid < 64) {
      int n = bh * 64 + tid;
      *(int4*)&sIdx[tid][0] = wi[n];
      *(float4*)&sKg[tid][0] = wg[n];
    }
    __syncthreads();
    int w4 = (tid & 15) * 4, kl = tid >> 4;
    int4 I0 = *(const int4*)&sIdx[w4][0];
    int4 I1 = *(const int4*)&sIdx[w4 + 1][0];
    int4 I2 = *(const int4*)&sIdx[w4 + 2][0];
    int4 I3 = *(const int4*)&sIdx[w4 + 3][0];
    float4 G0 = *(const float4*)&sKg[w4][0];
    float4 G1 = *(const float4*)&sKg[w4 + 1][0];
    float4 G2 = *(const float4*)&sKg[w4 + 2][0];
    float4 G3 = *(const float4*)&sKg[w4 + 3][0];
    float* ids = out + IDS_OFF;
    size_t base = (((size_t)b * KDIM + kq * 128 + kl) * HQ + h) * WQ + w4;
#pragma unroll
    for (int pass = 0; pass < 8; ++pass) {
      int k = kq * 128 + pass * 16 + kl;
      // reverse-order select chain = scatter last-wins semantics
      float4 v;
      v.x = (k == I0.w) ? G0.w : (k == I0.z) ? G0.z : (k == I0.y) ? G0.y : (k == I0.x) ? G0.x : 0.f;
      v.y = (k == I1.w) ? G1.w : (k == I1.z) ? G1.z : (k == I1.y) ? G1.y : (k == I1.x) ? G1.x : 0.f;
      v.z = (k == I2.w) ? G2.w : (k == I2.z) ? G2.z : (k == I2.y) ? G2.y : (k == I2.x) ? G2.x : 0.f;
      v.w = (k == I3.w) ? G3.w : (k == I3.z) ? G3.z : (k == I3.y) ? G3.y : (k == I3.x) ? G3.x : 0.f;
      *(float4*)&ids[base + (size_t)pass * 16 * 4096] = v;
    }
  }
}

// ---- finalize scalars (separate 1-block dispatch; stream order = no fence needed) ----
__global__ __launch_bounds__(64) void k_final(const double* __restrict__ accs,
                                              const int* __restrict__ hist,
                                              const float* __restrict__ pd,
                                              float* __restrict__ out) {
  if (threadIdx.x == 0) {
    float sumAbsD = 0.f;
#pragma unroll
    for (int i = 0; i < 8; ++i) sumAbsD += pd[i];
    double sumAbsZ = accs[0], sumSq = accs[1];
    float diff = (float)(sumSq / 2097152.0);
    out[DIFF_ENC_OFF] = diff;
    out[DIFF_DICT_OFF] = diff;
    out[NUM_STEPS_OFF] = 4.0f;
    out[MEAN_D_OFF] = sumAbsD / 32768.0f;
    out[MEAN_Z_OFF] = (float)(sumAbsZ / 16777216.0);
    int h0 = hist[0], h1 = hist[1], h2 = hist[2], h3 = hist[3], h4 = hist[4];
    out[NORM_Z_OFF] = (float)((double)(h1 + 2 * h2 + 3 * h3 + 4 * h4) / 32768.0);
    int cum = 0, res = 0;
    for (int v = 4; v >= 0; --v) {
      cum += hist[v];
      if (cum >= 327) { res = v; break; }
    }
    out[TOP_PCT_OFF] = (float)res;
    out[NUM_ZEROS_OFF] = (float)h0;
  }
}

extern "C" void kernel_launch(void* const* d_in, const int* in_sizes, int n_in,
                              void* d_out, int out_size, void* d_ws, size_t ws_size,
                              hipStream_t stream) {
  (void)in_sizes; (void)n_in; (void)out_size; (void)ws_size;
  const float* X = (const float*)d_in[0];    // [8,64,64,64]
  const float* D = (const float*)d_in[1];    // [64,512]
  float* out = (float*)d_out;
  float* W = (float*)d_ws;
  double* accs = (double*)d_ws;
  int* hist = (int*)W + 4;
  float* pd = W + WS_PD;
  float* DnT = W + WS_DNT;
  float* G = W + WS_G;
  float4* wgam = (float4*)(W + WS_WG);
  int4* widx = (int4*)(W + WS_WI);
  float* A0 = out;  // stage alpha0 in d_out[0 .. 16,777,216) — overwritten later

  hipLaunchKernelGGL(k_ga, dim3(4160), dim3(256), 0, stream, X, D, A0, G, DnT, pd, W);
  hipLaunchKernelGGL(k_omp, dim3(8192), dim3(256), 0, stream, A0, G, wgam, widx);
  hipLaunchKernelGGL(k_ei, dim3(2560), dim3(256), 0, stream, X, DnT, wgam, widx, out, accs, hist);
  hipLaunchKernelGGL(k_final, dim3(1), dim3(64), 0, stream, accs, hist, pd, out);
}